// Round 1
// baseline (257.510 us; speedup 1.0000x reference)
//
#include <hip/hip_runtime.h>
#include <hip/hip_bf16.h>
#include <stdint.h>

#define LQ 2048
#define LK 2048
#define DH 128
#define BQ 64          // q rows per workgroup
#define KB 128         // keys per staged tile
#define NT (LK / KB)   // 16 iterations
#define KROW 136       // LDS row stride in bf16 elems (272 B, 16B-aligned, pad kills 32-way conflicts)
#define LOG2E 1.44269504088896340736f
#define QSCALE 0.088388347648318447f   // 1/sqrt(128)

typedef __attribute__((ext_vector_type(8)))  short bf16x8;
typedef __attribute__((ext_vector_type(16))) float f32x16;
typedef __attribute__((ext_vector_type(4)))  float f32x4;

union FragAB { uint32_t u[4]; bf16x8 v; };

__device__ __forceinline__ uint32_t pack2_bf16(float lo, float hi) {
  union { __hip_bfloat16 b; uint16_t u; } a, c;
  a.b = __float2bfloat16(lo);
  c.b = __float2bfloat16(hi);
  return (uint32_t)a.u | ((uint32_t)c.u << 16);
}

__device__ __forceinline__ void stage_writes(uint16_t* Kb, uint16_t* Vb,
                                             const f32x4* st, int sbi, int sbj) {
#pragma unroll
  for (int j = 0; j < 2; ++j) {
    const int rowb = 4 * (sbi + 16 * j);
#pragma unroll
    for (int r = 0; r < 4; ++r) {       // K[key][d] row-major bf16
      uint32_t* kw = (uint32_t*)(Kb + (size_t)(rowb + r) * KROW + 4 * sbj);
      f32x4 v = st[j * 4 + r];
      kw[0] = pack2_bf16(v.x, v.y);
      kw[1] = pack2_bf16(v.z, v.w);
    }
#pragma unroll
    for (int c = 0; c < 4; ++c) {       // Vt[d][key] transposed bf16
      uint32_t* vw = (uint32_t*)(Vb + (size_t)(4 * sbj + c) * KROW + rowb);
      vw[0] = pack2_bf16(st[j * 4 + 0][c], st[j * 4 + 1][c]);
      vw[1] = pack2_bf16(st[j * 4 + 2][c], st[j * 4 + 3][c]);
    }
  }
}

__global__ __launch_bounds__(512, 2)
void fattn_kernel(const float* __restrict__ x1, const float* __restrict__ x2,
                  const float* __restrict__ qm, const float* __restrict__ uu,
                  float* __restrict__ out)
{
  __shared__ uint16_t ldsK[2][128 * KROW];   // 69632 B
  __shared__ uint16_t ldsV[2][128 * KROW];   // 69632 B  (total 136 KB)

  const int tid  = threadIdx.x;
  const int wv   = tid >> 6;
  const int lane = tid & 63;
  const int ln   = lane & 31;
  const int h    = lane >> 5;
  const int qsub = wv & 1;    // which 32-row q subtile
  const int ks   = wv >> 1;   // k-split index 0..3

  const int b    = blockIdx.x & 7;    // batch -> XCD locality for x2 slice
  const int qblk = blockIdx.x >> 3;
  const int qrow = qblk * BQ + qsub * 32 + ln;   // this lane's q row (softmax state owner)

  // ---- Q fragments: B-operand of S^T mfma (col=q=lane&31, k(d)=(lane>>5)*8+i), scaled by QSCALE*LOG2E
  FragAB qf[8];
  {
    const float* qp = x1 + ((size_t)(b * LQ + qrow)) * DH + h * 8;
    const float qs = QSCALE * LOG2E;
#pragma unroll
    for (int dc = 0; dc < 8; ++dc) {
      f32x4 a = *(const f32x4*)(qp + dc * 16);
      f32x4 c = *(const f32x4*)(qp + dc * 16 + 4);
      qf[dc].u[0] = pack2_bf16(a.x * qs, a.y * qs);
      qf[dc].u[1] = pack2_bf16(a.z * qs, a.w * qs);
      qf[dc].u[2] = pack2_bf16(c.x * qs, c.y * qs);
      qf[dc].u[3] = pack2_bf16(c.z * qs, c.w * qs);
    }
  }

  const int sbi = tid >> 5;   // staging: 4x4-block row group
  const int sbj = tid & 31;   // staging: 4x4-block col group
  const float* x2base = x2 + (size_t)b * LK * DH + sbj * 4;
  const float* ubase  = uu + ((size_t)(b * LQ + qrow)) * LK + ks * 32 + h * 4;
  const float* qmbase = qm + ((size_t)qrow) * LK + ks * 32 + h * 4;

  // ---- stage tile 0
  f32x4 st[8];
#pragma unroll
  for (int j = 0; j < 2; ++j)
#pragma unroll
    for (int r = 0; r < 4; ++r)
      st[j * 4 + r] = *(const f32x4*)(x2base + (size_t)(4 * (sbi + 16 * j) + r) * DH);

  f32x4 ucur[4];
#pragma unroll
  for (int g = 0; g < 4; ++g)
    ucur[g] = __builtin_nontemporal_load((const f32x4*)(ubase + g * 8));

  stage_writes(ldsK[0], ldsV[0], st, sbi, sbj);
  __syncthreads();

  float m_run = -1e30f, l_run = 0.f;
  f32x16 acco[4];
#pragma unroll
  for (int d2 = 0; d2 < 4; ++d2)
#pragma unroll
    for (int i = 0; i < 16; ++i) acco[d2][i] = 0.f;

  for (int t = 0; t < NT; ++t) {
    const int cb = t & 1;
    const uint16_t* Kb = ldsK[cb];
    const uint16_t* Vb = ldsV[cb];
    const int kb = t * KB;

    // qm loads for this iter (consumed after QK; mostly L2/L3 hits)
    f32x4 qmv[4];
#pragma unroll
    for (int g = 0; g < 4; ++g)
      qmv[g] = *(const f32x4*)(qmbase + (size_t)kb + g * 8);

    // prefetch next x2 tile + next u tile (in flight across whole compute phase)
    f32x4 unext[4];
    if (t + 1 < NT) {
#pragma unroll
      for (int j = 0; j < 2; ++j)
#pragma unroll
        for (int r = 0; r < 4; ++r)
          st[j * 4 + r] = *(const f32x4*)(x2base + (size_t)(kb + KB + 4 * (sbi + 16 * j) + r) * DH);
#pragma unroll
      for (int g = 0; g < 4; ++g)
        unext[g] = __builtin_nontemporal_load((const f32x4*)(ubase + (size_t)(kb + KB) + g * 8));
    }

    // ---- QK: S^T(32k x 32q) = K(32k x 16d) * Q^T(16d x 32q), 8 d-chunks
    f32x16 sacc;
#pragma unroll
    for (int i = 0; i < 16; ++i) sacc[i] = 0.f;
    const uint16_t* Krow = Kb + (size_t)(ks * 32 + ln) * KROW + h * 8;
#pragma unroll
    for (int dc = 0; dc < 8; ++dc) {
      bf16x8 af = *(const bf16x8*)(Krow + dc * 16);
      sacc = __builtin_amdgcn_mfma_f32_32x32x16_bf16(af, qf[dc].v, sacc, 0, 0, 0);
    }

    // ---- softmax (log2 domain; lane owns q-row; reg i -> key (i&3)+8*(i>>2)+4h)
#pragma unroll
    for (int g = 0; g < 4; ++g)
#pragma unroll
      for (int j2 = 0; j2 < 4; ++j2)
        sacc[g * 4 + j2] += qmv[g][j2] * LOG2E;
    float pm = sacc[0];
#pragma unroll
    for (int i = 1; i < 16; ++i) pm = fmaxf(pm, sacc[i]);
    pm = fmaxf(pm, __shfl_xor(pm, 32));
    const float mnew = fmaxf(m_run, pm);
    const float resc = __builtin_amdgcn_exp2f(m_run - mnew);
    m_run = mnew;
    float rs = 0.f;
#pragma unroll
    for (int i = 0; i < 16; ++i) {
      sacc[i] = __builtin_amdgcn_exp2f(sacc[i] - mnew);
      rs += sacc[i];
    }
    rs += __shfl_xor(rs, 32);
    l_run = l_run * resc + rs;          // denominator WITHOUT dropout

    // ---- dropout on numerator only
#pragma unroll
    for (int g = 0; g < 4; ++g)
#pragma unroll
      for (int j2 = 0; j2 < 4; ++j2)
        sacc[g * 4 + j2] = (ucur[g][j2] >= 0.1f) ? sacc[g * 4 + j2] : 0.f;

    // ---- pack bf16 pairs + exchange key-halves across lane 32 boundary
    uint32_t pr[4][2], sw[4][2];
#pragma unroll
    for (int g = 0; g < 4; ++g) {
      pr[g][0] = pack2_bf16(sacc[4 * g + 0], sacc[4 * g + 1]);
      pr[g][1] = pack2_bf16(sacc[4 * g + 2], sacc[4 * g + 3]);
      sw[g][0] = __shfl_xor(pr[g][0], 32);
      sw[g][1] = __shfl_xor(pr[g][1], 32);
    }
    FragAB bfr[2];
#pragma unroll
    for (int c = 0; c < 2; ++c) {
      bfr[c].u[0] = h ? sw[2 * c + 1][0] : pr[2 * c][0];
      bfr[c].u[1] = h ? sw[2 * c + 1][1] : pr[2 * c][1];
      bfr[c].u[2] = h ? pr[2 * c + 1][0] : sw[2 * c][0];
      bfr[c].u[3] = h ? pr[2 * c + 1][1] : sw[2 * c][1];
    }

    // ---- rescale running accumulator (per-lane, thanks to out^T layout)
#pragma unroll
    for (int d2 = 0; d2 < 4; ++d2)
#pragma unroll
      for (int i = 0; i < 16; ++i) acco[d2][i] *= resc;

    // ---- PV: out^T(32d x 32q) += V^T(32d x 16k) * P(16k x 32q)
#pragma unroll
    for (int d2 = 0; d2 < 4; ++d2) {
      const uint16_t* Vrow = Vb + (size_t)(d2 * 32 + ln) * KROW + ks * 32 + h * 8;
#pragma unroll
      for (int c = 0; c < 2; ++c) {
        bf16x8 av = *(const bf16x8*)(Vrow + c * 16);
        acco[d2] = __builtin_amdgcn_mfma_f32_32x32x16_bf16(av, bfr[c].v, acco[d2], 0, 0, 0);
      }
    }

    // ---- write next tile into other buffer, single barrier per iter
    if (t + 1 < NT) {
      stage_writes(ldsK[cb ^ 1], ldsV[cb ^ 1], st, sbi, sbj);
#pragma unroll
      for (int g = 0; g < 4; ++g) ucur[g] = unext[g];
    }
    __syncthreads();
  }

  // ---- k-split merge through LDS (reuse staging buffers; last barrier already passed)
  float* scr = (wv < 4) ? ((float*)ldsK + (size_t)wv * 4224)
                        : ((float*)ldsV + (size_t)(wv - 4) * 4224);
  scr[lane]      = m_run;
  scr[64 + lane] = l_run;
#pragma unroll
  for (int d2 = 0; d2 < 4; ++d2)
#pragma unroll
    for (int g = 0; g < 4; ++g) {
      f32x4 vv;
#pragma unroll
      for (int j2 = 0; j2 < 4; ++j2) vv[j2] = acco[d2][g * 4 + j2];
      *(f32x4*)(scr + 128 + (size_t)(d2 * 4 + g) * 256 + lane * 4) = vv;
    }
  __syncthreads();

  if (wv < 2) {
    const float* rg[4];
#pragma unroll
    for (int s2 = 0; s2 < 4; ++s2) {
      const int r = qsub + 2 * s2;
      rg[s2] = (r < 4) ? ((const float*)ldsK + (size_t)r * 4224)
                       : ((const float*)ldsV + (size_t)(r - 4) * 4224);
    }
    const float ms0 = rg[0][lane], ms1 = rg[1][lane], ms2 = rg[2][lane], ms3 = rg[3][lane];
    const float ls0 = rg[0][64 + lane], ls1 = rg[1][64 + lane];
    const float ls2 = rg[2][64 + lane], ls3 = rg[3][64 + lane];
    const float mM = fmaxf(fmaxf(ms0, ms1), fmaxf(ms2, ms3));
    const float e0 = __builtin_amdgcn_exp2f(ms0 - mM);
    const float e1 = __builtin_amdgcn_exp2f(ms1 - mM);
    const float e2 = __builtin_amdgcn_exp2f(ms2 - mM);
    const float e3 = __builtin_amdgcn_exp2f(ms3 - mM);
    const float lM = e0 * ls0 + e1 * ls1 + e2 * ls2 + e3 * ls3;
    const float inv = (1.0f / 0.9f) / lM;   // fold dropout 1/(1-p) into normalization
    float* op = out + ((size_t)(b * LQ + qrow)) * DH;
#pragma unroll
    for (int d2 = 0; d2 < 4; ++d2)
#pragma unroll
      for (int g = 0; g < 4; ++g) {
        const size_t off = 128 + (size_t)(d2 * 4 + g) * 256 + lane * 4;
        f32x4 a4 = e0 * *(const f32x4*)(rg[0] + off)
                 + e1 * *(const f32x4*)(rg[1] + off)
                 + e2 * *(const f32x4*)(rg[2] + off)
                 + e3 * *(const f32x4*)(rg[3] + off);
        a4 = a4 * inv;
        *(f32x4*)(op + d2 * 32 + 8 * g + 4 * h) = a4;
      }
  }
}

extern "C" void kernel_launch(void* const* d_in, const int* in_sizes, int n_in,
                              void* d_out, int out_size, void* d_ws, size_t ws_size,
                              hipStream_t stream) {
  (void)in_sizes; (void)n_in; (void)out_size; (void)d_ws; (void)ws_size;
  const float* x1 = (const float*)d_in[0];
  const float* x2 = (const float*)d_in[1];
  const float* qm = (const float*)d_in[2];
  const float* u  = (const float*)d_in[3];
  float* out = (float*)d_out;
  dim3 grid(256), block(512);
  fattn_kernel<<<grid, block, 0, stream>>>(x1, x2, qm, u, out);
}